// Round 3
// baseline (222.275 us; speedup 1.0000x reference)
//
#include <hip/hip_runtime.h>
#include <math.h>

// B=8, L=32, H=1024, N=32
// ws layout (floats):
#define NODE_OFF   0          // 8192*32
#define CHART_OFF  262144     // 8192*32
#define CN_OFF     524288     // 8192*32  (chart + node)
#define SPAN_OFF   786432     // 8192
#define D_OFF      794624     // 256*32   (diag lse part)
#define R_OFF      802816     // 32*32*32 (exp masked rules)
#define PART_OFF   835584     // 4*262144 (split-K node partials)
#define PARTS_OFF  1884160    // 4*8192   (split-K span partials)
#define FLAGS_OFF  1916928    // 8192 ints (per-cell ready flags)

// blocks 0..255: posnode row GEMM + D row; blocks 256..383: R = exp(masked rules) + flag clear
__global__ __launch_bounds__(256) void k_prep(
    const float* __restrict__ sh, const float* __restrict__ Wp,
    const float* __restrict__ bp, const float* __restrict__ pmask,
    const float* __restrict__ pu, const float* __restrict__ pum,
    const float* __restrict__ rs, const float* __restrict__ rm,
    float* __restrict__ D, float* __restrict__ R, int* __restrict__ flags) {
  int t = threadIdx.x;
  int bid = blockIdx.x;
  if (bid >= 256) {
    int idx = ((bid - 256) << 8) + t;
    R[idx] = __expf(rs[idx] + (rm[idx] - 1.0f) * 1e10f);
    if (idx < 8192) flags[idx] = 0;
    return;
  }
  __shared__ float rowl[1024];
  __shared__ float partl[8][33];
  __shared__ float posn[32];
#pragma unroll
  for (int k = 0; k < 4; ++k) rowl[t + 256 * k] = sh[bid * 1024 + t + 256 * k];
  __syncthreads();
  int c = t & 31, seg = t >> 5;
  float pacc = 0.f;
  for (int hh = 0; hh < 128; ++hh)
    pacc += rowl[seg * 128 + hh] * Wp[(seg * 128 + hh) * 32 + c];
  partl[seg][c] = pacc;
  __syncthreads();
  if (t < 32) {
    float s = 0.f;
#pragma unroll
    for (int k = 0; k < 8; ++k) s += partl[k][t];
    posn[t] = s + bp[t] + (pmask[t] - 1.0f) * 1e10f;
  }
  __syncthreads();
  if (t < 32) {
    float mq = posn[t];
#pragma unroll
    for (int m = 16; m >= 1; m >>= 1) mq = fmaxf(mq, __shfl_xor(mq, m, 32));
    float sum = 0.f;
#pragma unroll 8
    for (int q = 0; q < 32; ++q)
      sum += __expf(pu[t * 32 + q] + (pum[t * 32 + q] - 1.0f) * 1e15f + posn[q] - mq);
    D[bid * 32 + t] = mq + __logf(sum);
  }
}

// split-K node GEMM: grid 512 = 128 rowgroups(64 rows) x 4 k-slices(256 h).
__global__ __launch_bounds__(256) void k_node_main(
    const float* __restrict__ ph, const float* __restrict__ Wn,
    const float* __restrict__ Ws, float* __restrict__ part,
    float* __restrict__ partS) {
  __shared__ float A[64][132];
  __shared__ float Wl[128][32];
  __shared__ float Wsl[128];
  int t = threadIdx.x;
  int rg = blockIdx.x >> 2;
  int s = blockIdx.x & 3;
  int row0 = rg * 64;
  int h0 = s * 256;
  int tr = t >> 3, tc = t & 7;
  int r0 = tr * 2;
  int c = tc * 4;
  float acc[8] = {0.f, 0.f, 0.f, 0.f, 0.f, 0.f, 0.f, 0.f};
  float sp0 = 0.f, sp1 = 0.f;
  for (int hc = 0; hc < 2; ++hc) {
    int hb = h0 + hc * 128;
#pragma unroll
    for (int k = 0; k < 32; ++k) {
      int f = t + 256 * k;
      int rr = f >> 7, hh = f & 127;
      A[rr][hh] = ph[(row0 + rr) * 1024 + hb + hh];
    }
#pragma unroll
    for (int k = 0; k < 16; ++k) {
      int f = t + 256 * k;
      int hh = f >> 5, cc = f & 31;
      Wl[hh][cc] = Wn[(hb + hh) * 32 + cc];
    }
    if (t < 128) Wsl[t] = Ws[hb + t];
    __syncthreads();
#pragma unroll 2
    for (int h = 0; h < 128; ++h) {
      float a0 = A[r0][h], a1 = A[r0 + 1][h];
      float4 w = *(const float4*)&Wl[h][c];
      acc[0] += a0 * w.x; acc[1] += a0 * w.y; acc[2] += a0 * w.z; acc[3] += a0 * w.w;
      acc[4] += a1 * w.x; acc[5] += a1 * w.y; acc[6] += a1 * w.z; acc[7] += a1 * w.w;
      if (tc == 0) { float wv = Wsl[h]; sp0 += a0 * wv; sp1 += a1 * wv; }
    }
    __syncthreads();
  }
  int row = row0 + r0;
  float* po = part + s * 262144;
  *(float4*)&po[row * 32 + c] = make_float4(acc[0], acc[1], acc[2], acc[3]);
  *(float4*)&po[(row + 1) * 32 + c] = make_float4(acc[4], acc[5], acc[6], acc[7]);
  if (tc == 0) {
    partS[s * 8192 + row] = sp0;
    partS[s * 8192 + row + 1] = sp1;
  }
}

__global__ __launch_bounds__(256) void k_node_reduce(
    const float* __restrict__ part, const float* __restrict__ partS,
    const float* __restrict__ bn, const float* __restrict__ bs,
    const float* __restrict__ D, float* __restrict__ node,
    float* __restrict__ chart, float* __restrict__ cn,
    float* __restrict__ span) {
  int t = threadIdx.x;
  int row = blockIdx.x * 8 + (t >> 5);
  int c = t & 31;
  float v = bn[c];
#pragma unroll
  for (int s = 0; s < 4; ++s) v += part[s * 262144 + row * 32 + c];
  node[row * 32 + c] = v;
  int l = (row >> 5) & 31, m = row & 31;
  if (l == m) {
    float ch = v + D[(row >> 5) * 32 + c];
    chart[row * 32 + c] = ch;
    cn[row * 32 + c] = ch + v;
  }
  if (c == 0) {
    float sp = bs[0];
#pragma unroll
    for (int s = 0; s < 4; ++s) sp += partS[s * 8192 + row];
    span[row] = sp;
  }
}

// Persistent dataflow chain: 248 blocks x 1024 threads, all co-resident
// (248 <= 256 CUs). Cell (b,t0,e=t0+i) publishes an agent-scope flag; consumers
// spin. Dependencies only point to smaller spans -> acyclic -> no deadlock.
__global__ __launch_bounds__(1024) void k_chain(
    const float* __restrict__ node, const float* __restrict__ span,
    const float* __restrict__ R, float* __restrict__ chart,
    float* __restrict__ cn, int* __restrict__ flags,
    const int* __restrict__ sm, const float* __restrict__ rootm,
    float* __restrict__ out) {
  __shared__ float EL[31][32];
  __shared__ float ER[31][32];
  __shared__ float gam[32];
  __shared__ float S_lds[1024];
  __shared__ float vals[32];
  int tid = threadIdx.x;
  int bid = blockIdx.x;
  int j = tid >> 5, p = tid & 31;

  for (int i = 1; i < 32; ++i) {
    int nT = 32 - i;
    int nCells = nT * 8;
    if (bid >= nCells) continue;   // uniform per block
    int b = bid / nT, t0 = bid - b * nT;
    int rowL = b * 32 + t0;
    int e = t0 + i;
    // ---- spin on producer flags (wave 0 only: 2(i-1) <= 60 lanes) ----
    if (tid < 2 * (i - 1)) {
      int fi;
      if (tid < i - 1) fi = rowL * 32 + (t0 + 1 + tid);                 // left spans 1..i-1
      else             fi = (b * 32 + t0 + (tid - (i - 1)) + 1) * 32 + e; // right spans i-1..1
      while (__hip_atomic_load(&flags[fi], __ATOMIC_RELAXED, __HIP_MEMORY_SCOPE_AGENT) == 0)
        __builtin_amdgcn_s_sleep(1);
    }
    __syncthreads();
    // ---- load left/right (agent scope: bypass non-coherent caches) ----
    bool act = j < i;
    float left = 0.f, right = 0.f, beta = 0.f;
    if (act) {
      left  = __hip_atomic_load(&cn[(rowL * 32 + t0 + j) * 32 + p], __ATOMIC_RELAXED, __HIP_MEMORY_SCOPE_AGENT);
      right = __hip_atomic_load(&cn[((b * 32 + t0 + j + 1) * 32 + e) * 32 + p], __ATOMIC_RELAXED, __HIP_MEMORY_SCOPE_AGENT);
      float alpha = left;
      beta = right;
#pragma unroll
      for (int m = 16; m >= 1; m >>= 1) {
        alpha = fmaxf(alpha, __shfl_xor(alpha, m, 32));
        beta = fmaxf(beta, __shfl_xor(beta, m, 32));
      }
      if (p == 0) gam[j] = alpha + beta;
    }
    __syncthreads();
    float G = gam[0];
    for (int jj = 1; jj < i; ++jj) G = fmaxf(G, gam[jj]);   // LDS broadcast
    if (act) {
      EL[j][p] = __expf(left + beta - G);
      ER[j][p] = __expf(right - beta);
    }
    __syncthreads();
    {   // S[p,q] = sum_j EL[j][p]*ER[j][q]; thread (j,p) computes S[j][p]
      float S = 0.f;
      for (int jj = 0; jj < i; ++jj) S += EL[jj][j] * ER[jj][p];
      S_lds[tid] = S;
    }
    __syncthreads();
    {   // inner[a] = G + log(sum_pq R[a][p][q]*S[p][q]); group j = symbol a
      const float* Ra = R + (j << 10);
      float pt = 0.f;
#pragma unroll
      for (int k = 0; k < 32; ++k) pt += Ra[(k << 5) + p] * S_lds[(k << 5) + p];
#pragma unroll
      for (int m = 16; m >= 1; m >>= 1) pt += __shfl_xor(pt, m, 32);
      if (p == 0) {
        int oi = (rowL * 32 + e) * 32 + j;
        float nd = node[oi];
        float v = G + __logf(pt) + nd + span[rowL * 32 + e];
        __hip_atomic_store(&chart[oi], v, __ATOMIC_RELAXED, __HIP_MEMORY_SCOPE_AGENT);
        __hip_atomic_store(&cn[oi], v + nd, __ATOMIC_RELAXED, __HIP_MEMORY_SCOPE_AGENT);
        if (i == 31) vals[j] = v;
      }
    }
    __syncthreads();   // vmcnt(0) drain: cell values committed before flag
    if (tid == 0)
      __hip_atomic_store(&flags[rowL * 32 + e], 1, __ATOMIC_RELEASE, __HIP_MEMORY_SCOPE_AGENT);
  }
  // logits: blocks 0..7 computed (b=bid, 0, 31); its left-dep spins covered all
  // (b,0,span) cells, so chart[(b,0,len-1)] is final for any len.
  if (bid < 8 && tid < 32) {
    int len = 0;
#pragma unroll
    for (int l = 0; l < 32; ++l) len += sm[bid * 32 + l];
    float cv = (len == 32) ? vals[tid]
        : __hip_atomic_load(&chart[((bid * 32) * 32 + (len - 1)) * 32 + tid],
                            __ATOMIC_RELAXED, __HIP_MEMORY_SCOPE_AGENT);
    out[bid * 32 + tid] = cv + (rootm[tid] - 1.0f) * 1e10f;
  }
}

extern "C" void kernel_launch(void* const* d_in, const int* in_sizes, int n_in,
                              void* d_out, int out_size, void* d_ws, size_t ws_size,
                              hipStream_t stream) {
  const float* ph    = (const float*)d_in[0];
  const float* sh    = (const float*)d_in[1];
  const int*   sm    = (const int*)  d_in[2];
  const float* Wp    = (const float*)d_in[3];
  const float* bp    = (const float*)d_in[4];
  const float* Wn    = (const float*)d_in[5];
  const float* bn    = (const float*)d_in[6];
  const float* Ws    = (const float*)d_in[7];
  const float* bs    = (const float*)d_in[8];
  const float* rs    = (const float*)d_in[9];
  const float* pu    = (const float*)d_in[10];
  const float* rootm = (const float*)d_in[11];
  const float* pm    = (const float*)d_in[12];
  const float* rm    = (const float*)d_in[13];
  const float* pum   = (const float*)d_in[14];
  float* out = (float*)d_out;

  float* ws    = (float*)d_ws;
  float* node  = ws + NODE_OFF;
  float* chart = ws + CHART_OFF;
  float* cn    = ws + CN_OFF;
  float* span  = ws + SPAN_OFF;
  float* D     = ws + D_OFF;
  float* R     = ws + R_OFF;
  float* part  = ws + PART_OFF;
  float* partS = ws + PARTS_OFF;
  int*   flags = (int*)(ws + FLAGS_OFF);

  k_prep<<<384, 256, 0, stream>>>(sh, Wp, bp, pm, pu, pum, rs, rm, D, R, flags);
  k_node_main<<<512, 256, 0, stream>>>(ph, Wn, Ws, part, partS);
  k_node_reduce<<<1024, 256, 0, stream>>>(part, partS, bn, bs, D, node, chart, cn, span);
  k_chain<<<248, 1024, 0, stream>>>(node, span, R, chart, cn, flags, sm, rootm, out);
}

// Round 4
// 198.387 us; speedup vs baseline: 1.1204x; 1.1204x over previous
//
#include <hip/hip_runtime.h>
#include <math.h>

// B=8, L=32, H=1024, N=32
// ws layout (floats):
#define NODE_OFF   0          // 8192*32
#define CHART_OFF  262144     // 8192*32
#define CN_OFF     524288     // 8192*32  (chart + node)
#define SPAN_OFF   786432     // 8192
#define D_OFF      794624     // 256*32   (diag lse part)
#define R_OFF      802816     // 32*32*32 (exp masked rules)
#define PART_OFF   835584     // 4*262144 (split-K node partials)
#define PARTS_OFF  1884160    // 4*8192   (split-K span partials)
#define CNT_OFF    1916928    // 256 ints: cnt[b*32+i] = finished cells of span i, batch b

// Fused front kernel, 896 blocks x 256:
//  blocks 0..511   : node split-K GEMM (128 rowgroups x 4 k-slices)
//  blocks 512..767 : posnode row GEMM + D row
//  blocks 768..895 : R = exp(masked rules) + counter clear
__global__ __launch_bounds__(256) void k_pre(
    const float* __restrict__ ph, const float* __restrict__ Wn,
    const float* __restrict__ Ws, const float* __restrict__ sh,
    const float* __restrict__ Wp, const float* __restrict__ bp,
    const float* __restrict__ pmask, const float* __restrict__ pu,
    const float* __restrict__ pum, const float* __restrict__ rs,
    const float* __restrict__ rm, float* __restrict__ part,
    float* __restrict__ partS, float* __restrict__ D,
    float* __restrict__ R, int* __restrict__ cnt) {
  __shared__ float smem[12672];   // 50688 B, aliased per branch
  int t = threadIdx.x;
  int bid = blockIdx.x;
  if (bid >= 768) {               // ---- R exp + counter clear ----
    int idx = ((bid - 768) << 8) + t;
    R[idx] = __expf(rs[idx] + (rm[idx] - 1.0f) * 1e10f);
    if (idx < 256) cnt[idx] = 0;
    return;
  }
  if (bid >= 512) {               // ---- posnode + D ----
    float* rowl = smem;           // 1024
    float* partl = smem + 1024;   // 8*33
    float* posn = smem + 1288;    // 32
    int row = bid - 512;
#pragma unroll
    for (int k = 0; k < 4; ++k) rowl[t + 256 * k] = sh[row * 1024 + t + 256 * k];
    __syncthreads();
    int c = t & 31, seg = t >> 5;
    float pacc = 0.f;
    for (int hh = 0; hh < 128; ++hh)
      pacc += rowl[seg * 128 + hh] * Wp[(seg * 128 + hh) * 32 + c];
    partl[seg * 33 + c] = pacc;
    __syncthreads();
    if (t < 32) {
      float s = 0.f;
#pragma unroll
      for (int k = 0; k < 8; ++k) s += partl[k * 33 + t];
      posn[t] = s + bp[t] + (pmask[t] - 1.0f) * 1e10f;
    }
    __syncthreads();
    if (t < 32) {
      float mq = posn[t];
#pragma unroll
      for (int m = 16; m >= 1; m >>= 1) mq = fmaxf(mq, __shfl_xor(mq, m, 32));
      float sum = 0.f;
#pragma unroll 8
      for (int q = 0; q < 32; ++q)
        sum += __expf(pu[t * 32 + q] + (pum[t * 32 + q] - 1.0f) * 1e15f + posn[q] - mq);
      D[row * 32 + t] = mq + __logf(sum);
    }
    return;
  }
  // ---- node split-K GEMM ----
  float (*A)[132] = (float(*)[132])smem;            // 64x132
  float (*Wl)[32] = (float(*)[32])(smem + 8448);    // 128x32
  float* Wsl = smem + 12544;                        // 128
  int rg = bid >> 2;
  int s = bid & 3;
  int row0 = rg * 64;
  int h0 = s * 256;
  int tr = t >> 3, tc = t & 7;
  int r0 = tr * 2;
  int c = tc * 4;
  float acc[8] = {0.f, 0.f, 0.f, 0.f, 0.f, 0.f, 0.f, 0.f};
  float sp0 = 0.f, sp1 = 0.f;
  for (int hc = 0; hc < 2; ++hc) {
    int hb = h0 + hc * 128;
#pragma unroll
    for (int k = 0; k < 32; ++k) {
      int f = t + 256 * k;
      int rr = f >> 7, hh = f & 127;
      A[rr][hh] = ph[(row0 + rr) * 1024 + hb + hh];
    }
#pragma unroll
    for (int k = 0; k < 16; ++k) {
      int f = t + 256 * k;
      int hh = f >> 5, cc = f & 31;
      Wl[hh][cc] = Wn[(hb + hh) * 32 + cc];
    }
    if (t < 128) Wsl[t] = Ws[hb + t];
    __syncthreads();
#pragma unroll 2
    for (int h = 0; h < 128; ++h) {
      float a0 = A[r0][h], a1 = A[r0 + 1][h];
      float4 w = *(const float4*)&Wl[h][c];
      acc[0] += a0 * w.x; acc[1] += a0 * w.y; acc[2] += a0 * w.z; acc[3] += a0 * w.w;
      acc[4] += a1 * w.x; acc[5] += a1 * w.y; acc[6] += a1 * w.z; acc[7] += a1 * w.w;
      if (tc == 0) { float wv = Wsl[h]; sp0 += a0 * wv; sp1 += a1 * wv; }
    }
    __syncthreads();
  }
  int row = row0 + r0;
  float* po = part + s * 262144;
  *(float4*)&po[row * 32 + c] = make_float4(acc[0], acc[1], acc[2], acc[3]);
  *(float4*)&po[(row + 1) * 32 + c] = make_float4(acc[4], acc[5], acc[6], acc[7]);
  if (tc == 0) {
    partS[s * 8192 + row] = sp0;
    partS[s * 8192 + row + 1] = sp1;
  }
}

__global__ __launch_bounds__(256) void k_node_reduce(
    const float* __restrict__ part, const float* __restrict__ partS,
    const float* __restrict__ bn, const float* __restrict__ bs,
    const float* __restrict__ D, float* __restrict__ node,
    float* __restrict__ chart, float* __restrict__ cn,
    float* __restrict__ span) {
  int t = threadIdx.x;
  int row = blockIdx.x * 8 + (t >> 5);
  int c = t & 31;
  float v = bn[c];
#pragma unroll
  for (int s = 0; s < 4; ++s) v += part[s * 262144 + row * 32 + c];
  node[row * 32 + c] = v;
  int l = (row >> 5) & 31, m = row & 31;
  if (l == m) {
    float ch = v + D[(row >> 5) * 32 + c];
    chart[row * 32 + c] = ch;
    cn[row * 32 + c] = ch + v;
  }
  if (c == 0) {
    float sp = bs[0];
#pragma unroll
    for (int s = 0; s < 4; ++s) sp += partS[s * 8192 + row];
    span[row] = sp;
  }
}

// Persistent dataflow chain: 248 blocks x 1024 threads (all co-resident).
// Stage gating: per-(batch,span) counters; one lane polls one word.
__global__ __launch_bounds__(1024) void k_chain(
    const float* __restrict__ node, const float* __restrict__ span,
    const float* __restrict__ R, float* __restrict__ chart,
    float* __restrict__ cn, int* __restrict__ cnt,
    const int* __restrict__ sm, const float* __restrict__ rootm,
    float* __restrict__ out) {
  __shared__ float EL[31][32];
  __shared__ float ER[31][32];
  __shared__ float gam[32];
  __shared__ float S_lds[1024];
  __shared__ float vals[32];
  __shared__ float G_s;
  int tid = threadIdx.x;
  int bid = blockIdx.x;
  int j = tid >> 5, p = tid & 31;
  int lastStage = 31 - (bid >> 3);   // bid < 8*(32-i)  <=>  i <= 31 - bid/8

  for (int i = 1; i <= lastStage; ++i) {
    int nT = 32 - i;
    int b = bid / nT, t0 = bid - b * nT;
    int rowL = b * 32 + t0;
    int e = t0 + i;
    // ---- wait: all span-(i-1) cells of batch b done (induction covers <i-1) ----
    if (i > 1) {
      if (tid == 0) {
        int target = nT + 1;   // cells at span i-1 per batch
        while (__hip_atomic_load(&cnt[b * 32 + (i - 1)], __ATOMIC_RELAXED,
                                 __HIP_MEMORY_SCOPE_AGENT) < target)
          __builtin_amdgcn_s_sleep(1);
      }
      __syncthreads();
    }
    // ---- load operands (coherence-point atomics), per-split maxes ----
    bool act = j < i;
    float left = 0.f, right = 0.f, beta = 0.f;
    if (act) {
      left = __hip_atomic_load(&cn[(rowL * 32 + t0 + j) * 32 + p],
                               __ATOMIC_RELAXED, __HIP_MEMORY_SCOPE_AGENT);
      right = __hip_atomic_load(&cn[((b * 32 + t0 + j + 1) * 32 + e) * 32 + p],
                                __ATOMIC_RELAXED, __HIP_MEMORY_SCOPE_AGENT);
      float alpha = left;
      beta = right;
#pragma unroll
      for (int m = 16; m >= 1; m >>= 1) {
        alpha = fmaxf(alpha, __shfl_xor(alpha, m, 32));
        beta = fmaxf(beta, __shfl_xor(beta, m, 32));
      }
      if (p == 0) gam[j] = alpha + beta;
    }
    __syncthreads();
    // ---- G = max_j gam[j] via shfl tree (wave 0) ----
    if (tid < 32) {
      float g = (tid < i) ? gam[tid] : -3.0e38f;
#pragma unroll
      for (int m = 16; m >= 1; m >>= 1) g = fmaxf(g, __shfl_xor(g, m, 32));
      if (tid == 0) G_s = g;
    }
    __syncthreads();
    float G = G_s;
    if (act) {
      EL[j][p] = __expf(left + beta - G);
      ER[j][p] = __expf(right - beta);
    }
    __syncthreads();
    {   // S[p,q] = sum_j EL[j][p]*ER[j][q]; thread (j,p) -> S[j][p]
      float S = 0.f;
      for (int jj = 0; jj < i; ++jj) S += EL[jj][j] * ER[jj][p];
      S_lds[tid] = S;
    }
    __syncthreads();
    {   // inner[a] = G + log(sum_pq R[a][p][q]*S[p][q]); wave-group j = symbol a
      const float* Ra = R + (j << 10);
      float pt = 0.f;
#pragma unroll
      for (int k = 0; k < 32; ++k) pt += Ra[(k << 5) + p] * S_lds[(k << 5) + p];
#pragma unroll
      for (int m = 16; m >= 1; m >>= 1) pt += __shfl_xor(pt, m, 32);
      if (p == 0) {
        int oi = (rowL * 32 + e) * 32 + j;
        float nd = node[oi];
        float v = G + __logf(pt) + nd + span[rowL * 32 + e];
        __hip_atomic_store(&chart[oi], v, __ATOMIC_RELAXED, __HIP_MEMORY_SCOPE_AGENT);
        __hip_atomic_store(&cn[oi], v + nd, __ATOMIC_RELAXED, __HIP_MEMORY_SCOPE_AGENT);
        if (i == 31) vals[j] = v;
      }
    }
    __syncthreads();   // vmcnt-drain: bypass-stores globally visible before the add
    if (tid == 0)
      __hip_atomic_fetch_add(&cnt[b * 32 + i], 1, __ATOMIC_RELEASE,
                             __HIP_MEMORY_SCOPE_AGENT);
  }
  // logits: blocks 0..7 ran through i=31 (b=bid); all spans <=30 proven done.
  if (bid < 8 && tid < 32) {
    int len = 0;
#pragma unroll
    for (int l = 0; l < 32; ++l) len += sm[bid * 32 + l];
    float cv = (len == 32) ? vals[tid]
        : __hip_atomic_load(&chart[((bid * 32) * 32 + (len - 1)) * 32 + tid],
                            __ATOMIC_RELAXED, __HIP_MEMORY_SCOPE_AGENT);
    out[bid * 32 + tid] = cv + (rootm[tid] - 1.0f) * 1e10f;
  }
}

extern "C" void kernel_launch(void* const* d_in, const int* in_sizes, int n_in,
                              void* d_out, int out_size, void* d_ws, size_t ws_size,
                              hipStream_t stream) {
  const float* ph    = (const float*)d_in[0];
  const float* sh    = (const float*)d_in[1];
  const int*   sm    = (const int*)  d_in[2];
  const float* Wp    = (const float*)d_in[3];
  const float* bp    = (const float*)d_in[4];
  const float* Wn    = (const float*)d_in[5];
  const float* bn    = (const float*)d_in[6];
  const float* Ws    = (const float*)d_in[7];
  const float* bs    = (const float*)d_in[8];
  const float* rs    = (const float*)d_in[9];
  const float* pu    = (const float*)d_in[10];
  const float* rootm = (const float*)d_in[11];
  const float* pm    = (const float*)d_in[12];
  const float* rm    = (const float*)d_in[13];
  const float* pum   = (const float*)d_in[14];
  float* out = (float*)d_out;

  float* ws    = (float*)d_ws;
  float* node  = ws + NODE_OFF;
  float* chart = ws + CHART_OFF;
  float* cn    = ws + CN_OFF;
  float* span  = ws + SPAN_OFF;
  float* D     = ws + D_OFF;
  float* R     = ws + R_OFF;
  float* part  = ws + PART_OFF;
  float* partS = ws + PARTS_OFF;
  int*   cnt   = (int*)(ws + CNT_OFF);

  k_pre<<<896, 256, 0, stream>>>(ph, Wn, Ws, sh, Wp, bp, pm, pu, pum, rs, rm,
                                 part, partS, D, R, cnt);
  k_node_reduce<<<1024, 256, 0, stream>>>(part, partS, bn, bs, D, node, chart, cn, span);
  k_chain<<<248, 1024, 0, stream>>>(node, span, R, chart, cn, cnt, sm, rootm, out);
}